// Round 11
// baseline (381.995 us; speedup 1.0000x reference)
//
#include <hip/hip_runtime.h>
#include <hip/hip_bf16.h>

#define N_NODES    100000
#define N_EDGES    1600000
#define IN_CH      128
#define HID        64
#define N_LAYERS   4
#define OUT_CH     10
#define NUM_GRAPHS 128
#define BN_EPS     1e-5f
#define CAP        64             // padded CSR row capacity; P(deg>64) ~ 1e-19 at Poisson(16)
#define NREP       8              // pooled replicas (cuts per-address atomic chains 8x)
#define NBKT       256            // dst>>9 -> buckets 0..195 (256 slots for pow2 LDS)
#define NBUCK      196            // ceil(100000 / 512) actual buckets
#define EPB        2048           // edges per block in partition kernels
#define PNB        782            // ceil(1.6M / 2048)
#define SUBCAP     2688           // per-128-node-slice edge capacity (mean 2048, sd 45: 14 sigma)
#define ZB         360            // zero blocks inside stage1
#define P0B        6250           // proj0 blocks inside stage1
#define NWMAT      8              // fragment matrices: 4 W2 + 3 W1n + W1f(K=128)

typedef __hip_bfloat16 bf16;
typedef unsigned int uint32;
typedef float f32x2 __attribute__((ext_vector_type(2)));
typedef float f32x4 __attribute__((ext_vector_type(4)));
typedef short s16x8 __attribute__((ext_vector_type(8)));   // 8 bf16 (4 VGPRs)

__device__ __forceinline__ float bf2f(bf16 v) { return __bfloat162float(v); }
// unpack packed bf16x2 dword -> f32x2 pair (bf16 -> f32 is <<16)
__device__ __forceinline__ f32x2 unpk2(uint32 p) {
    f32x2 r;
    r.x = __uint_as_float(p << 16);
    r.y = __uint_as_float(p & 0xffff0000u);
    return r;
}
__device__ __forceinline__ short f2bs(float f) {
    bf16 b = __float2bfloat16(f);
    return *reinterpret_cast<short*>(&b);
}

// ---------------- prep: ghist zero + weight fragment conversion --------------
// block 0: zero ghist. blocks 1..8: convert one weight matrix to MFMA B-frag
// order (bf16). mi 0..6: 64x64 (4 W2, 3 W1n), K=64 (2 k-slices x 4 tiles).
// mi 7: W1f 128x64, K=128 (4 k-slices x 4 tiles). Runs BEFORE stage1 because
// stage1's proj0 blocks consume the W1f fragments (no same-kernel ordering).
__global__ void prep(int* __restrict__ ghist,
                     const float* __restrict__ W1f, const float* __restrict__ W2f,
                     const float* __restrict__ W2r, const float* __restrict__ W1r,
                     bf16* __restrict__ wfrag) {
    const int bid = blockIdx.x, t = threadIdx.x;  // 9 blocks x 256 threads
    if (bid == 0) { ghist[t] = 0; return; }
    const int mi = bid - 1;                       // 0..7
    if (mi < 7) {
        const float* W = (mi == 0) ? W2f
                       : (mi <= 3) ? W2r + (long)(mi - 1) * HID * HID
                                   : W1r + (long)(mi - 4) * HID * HID;
        bf16* out = wfrag + mi * HID * HID;
        for (int u = 0; u < 2; u++) {
            int idx = u * 256 + t;                // (tile*2+ks)*64 + lane
            int lane = idx & 63, tk = idx >> 6;
            int kbase = (tk & 1) * 32 + 8 * (lane >> 4);
            int c = (tk >> 1) * 16 + (lane & 15);
            #pragma unroll
            for (int j = 0; j < 8; j++)
                out[idx * 8 + j] = __float2bfloat16(W[(kbase + j) * 64 + c]);
        }
    } else {
        bf16* out = wfrag + 7 * HID * HID;        // W1f: 1024 frag groups
        for (int u = 0; u < 4; u++) {
            int idx = u * 256 + t;                // (tile*4+ks)*64 + lane
            int lane = idx & 63, tk = idx >> 6;   // 0..15
            int kbase = (tk & 3) * 32 + 8 * (lane >> 4);
            int c = (tk >> 2) * 16 + (lane & 15);
            #pragma unroll
            for (int j = 0; j < 8; j++)
                out[idx * 8 + j] = __float2bfloat16(W1f[(kbase + j) * 64 + c]);
        }
    }
}

// ---------------- stage1: fused bhist | zero | proj0(MFMA) -------------------
// blocks [0,782): edge-bucket histogram; [782,1142): zero accum region;
// [1142,7392): layer-0 projection ybf = bf16(x @ W1f) on matrix cores:
// 16 nodes/block, x cast to bf16 in LDS, 4 mfma_16x16x32 per wave (K=128).
__global__ void stage1(const int* __restrict__ dst, int* __restrict__ ghist,
                       int* __restrict__ zp, int zn,
                       const float* __restrict__ x, const bf16* __restrict__ w1ffrag,
                       bf16* __restrict__ ybf) {
    const int bid = blockIdx.x;
    const int t = threadIdx.x;
    if (bid < PNB) {
        // ---- bhist ----
        __shared__ int h[NBKT];
        h[t] = 0;
        __syncthreads();
        long base = (long)bid * EPB;
        for (int u = 0; u < 8; u++) {
            long e = base + u * 256 + t;
            if (e < N_EDGES) atomicAdd(&h[dst[e] >> 9], 1);
        }
        __syncthreads();
        if (h[t]) atomicAdd(&ghist[t], h[t]);
    } else if (bid < PNB + ZB) {
        // ---- zero accumulators (pooled .. zstats; ghist excluded) ----
        int i = (bid - PNB) * 256 + t;
        const int st = ZB * 256;
        for (; i < zn; i += st) zp[i] = 0;
    } else {
        // ---- proj0 via MFMA: 16 nodes per block ----
        __shared__ __align__(16) short Xsh[16][136];  // 4352 B; 272-B row stride
        const int wave = t >> 6, lane = t & 63;
        const int nb = (bid - PNB - ZB) * 16;         // 6250*16 == 100000
        {   // stage x -> bf16 LDS: thread = (row: t>>4, cols: 8*(t&15)..+8)
            int row = t >> 4, c0 = (t & 15) * 8;
            const float* xr = x + (long)(nb + row) * IN_CH + c0;
            f32x4 v0 = *(const f32x4*)(xr);
            f32x4 v1 = *(const f32x4*)(xr + 4);
            s16x8 b;
            b[0] = f2bs(v0.x); b[1] = f2bs(v0.y); b[2] = f2bs(v0.z); b[3] = f2bs(v0.w);
            b[4] = f2bs(v1.x); b[5] = f2bs(v1.y); b[6] = f2bs(v1.z); b[7] = f2bs(v1.w);
            *(s16x8*)&Xsh[row][c0] = b;
        }
        __syncthreads();
        const int c15 = lane & 15, g16 = lane >> 4;
        const s16x8* wq = (const s16x8*)w1ffrag;
        f32x4 yac = {0.f, 0.f, 0.f, 0.f};
        #pragma unroll
        for (int ks = 0; ks < 4; ks++) {
            s16x8 a = *(const s16x8*)((const char*)Xsh + c15 * 272 + ks * 64 + g16 * 16);
            yac = __builtin_amdgcn_mfma_f32_16x16x32_bf16(
                a, wq[(wave * 4 + ks) * 64 + lane], yac, 0, 0, 0);
        }
        #pragma unroll
        for (int i = 0; i < 4; i++)               // D: col=lane&15, row=4*(lane>>4)+i
            ybf[(long)(nb + 4 * g16 + i) * 64 + 16 * wave + c15] = __float2bfloat16(yac[i]);
    }
}

// ---------------- bucket scan + cntg (binary search) + ybf pad-row zero ------
__global__ void bscan(const int* __restrict__ ghist, int* __restrict__ gcursor,
                      int* __restrict__ gbase,
                      const int* __restrict__ batch, int* __restrict__ cntg,
                      bf16* __restrict__ ybfA, bf16* __restrict__ ybfB) {
    __shared__ int sh[NBKT];
    int t = threadIdx.x;                          // 256 threads
    int v = ghist[t];
    sh[t] = v;
    __syncthreads();
    for (int off = 1; off < NBKT; off <<= 1) {
        int a = (t >= off) ? sh[t - off] : 0;
        __syncthreads();
        sh[t] += a;
        __syncthreads();
    }
    gcursor[t] = sh[t] - v;                       // exclusive bucket base (bpart cursor)
    gbase[t]   = sh[t] - v;                       // immutable copy for bfill
    if (t < NUM_GRAPHS) {                         // per-graph node counts
        int g = t, lo = 0, hi = N_NODES;
        while (lo < hi) { int m = (lo + hi) >> 1; if (batch[m] < g) lo = m + 1; else hi = m; }
        int lb = lo;
        lo = 0; hi = N_NODES;
        while (lo < hi) { int m = (lo + hi) >> 1; if (batch[m] < g + 1) lo = m + 1; else hi = m; }
        cntg[g] = lo - lb;
    }
    if (t < HID) {                                // sentinel zero-row for tail-free gather
        ybfA[(long)N_NODES * HID + t] = __float2bfloat16(0.f);
        ybfB[(long)N_NODES * HID + t] = __float2bfloat16(0.f);
    }
}

// ---------------- partition edges into bucket order (packed 4-B records) -----
// record = src | (dst&511)<<17  (src < 2^17, local dst < 2^9)
__global__ void bpart(const int* __restrict__ src, const int* __restrict__ dst,
                      int* __restrict__ gcursor, int* __restrict__ epart) {
    __shared__ int h[NBKT];
    __shared__ int cur[NBKT];
    int t = threadIdx.x;
    h[t] = 0;
    __syncthreads();
    long base = (long)blockIdx.x * EPB;
    int myd[8], mys[8];
    for (int u = 0; u < 8; u++) {
        long e = base + u * 256 + t;
        if (e < N_EDGES) {
            myd[u] = dst[e];
            mys[u] = src[e];
            atomicAdd(&h[myd[u] >> 9], 1);
        } else myd[u] = -1;
    }
    __syncthreads();
    if (h[t]) cur[t] = atomicAdd(&gcursor[t], h[t]);
    __syncthreads();
    for (int u = 0; u < 8; u++) {
        if (myd[u] >= 0) {
            int pos = atomicAdd(&cur[myd[u] >> 9], 1);
            epart[pos] = mys[u] | ((myd[u] & 511) << 17);
        }
    }
}

// ---------------- per-slice LDS counting sort -> coalesced CSR fill ----------
// Rows now padded to a multiple of 8 (the gather's quantum) instead of 32:
// mean padded degree 32 -> ~19.5, cutting gather VMEM/unpack ~39%. Partial
// 128B-line row writes add ~13MB RFO (~2us) -- cheap vs the gather savings.
__global__ __launch_bounds__(256)
void bfill(const int* __restrict__ epart, const int* __restrict__ gbase,
           const int* __restrict__ ghist, int* __restrict__ cnt,
           int* __restrict__ col) {
    __shared__ int lcnt[128];
    __shared__ int loff[128];
    __shared__ int lsrc[SUBCAP];
    const int b = blockIdx.x >> 2;                // 512-node bucket 0..195
    const int q = blockIdx.x & 3;                 // 128-node slice 0..3
    const int t = threadIdx.x;                    // 256 threads
    const int n0 = (b << 9) + (q << 7);
    if (n0 >= N_NODES) return;                    // uniform: whole block exits
    const int nN = min(128, N_NODES - n0);
    const int base = gbase[b];
    const int m = ghist[b];
    const int lo = q << 7;                        // local9 range [lo, lo+128)

    if (t < 128) lcnt[t] = 0;
    __syncthreads();
    // pass 1: per-node degree (slice filter)
    for (int e = t; e < m; e += 256) {
        int ln = (int)((uint32)epart[base + e] >> 17) - lo;
        if ((uint32)ln < 128u) atomicAdd(&lcnt[ln], 1);
    }
    __syncthreads();
    // inclusive Hillis-Steele scan over 128 counts
    if (t < 128) loff[t] = lcnt[t];
    __syncthreads();
    for (int off = 1; off < 128; off <<= 1) {
        int a = (t < 128 && t >= off) ? loff[t - off] : 0;
        __syncthreads();
        if (t < 128) loff[t] += a;
        __syncthreads();
    }
    int ex = 0;
    if (t < 128) ex = loff[t] - lcnt[t];          // exclusive offset
    __syncthreads();
    if (t < 128) { loff[t] = ex; lcnt[t] = 0; }   // lcnt reused as cursor
    __syncthreads();
    // pass 2: scatter srcs into per-node runs
    for (int e = t; e < m; e += 256) {
        uint32 v = (uint32)epart[base + e];
        int ln = (int)(v >> 17) - lo;
        if ((uint32)ln < 128u) {
            int slot = atomicAdd(&lcnt[ln], 1);
            lsrc[loff[ln] + slot] = (int)(v & 0x1FFFFu);
        }
    }
    __syncthreads();
    // write rows: data + sentinel pad to deg8, int4 stores; plus cnt
    if (t < nN) {
        int deg = lcnt[t];
        int st  = loff[t];
        int n   = n0 + t;
        cnt[n] = deg;
        int d8 = (deg + 7) & ~7;
        int* row = col + n * CAP;
        for (int s4 = 0; s4 < d8; s4 += 4) {
            int4 qv;
            qv.x = (s4 + 0 < deg) ? lsrc[st + s4 + 0] : N_NODES;
            qv.y = (s4 + 1 < deg) ? lsrc[st + s4 + 1] : N_NODES;
            qv.z = (s4 + 2 < deg) ? lsrc[st + s4 + 2] : N_NODES;
            qv.w = (s4 + 3 < deg) ? lsrc[st + s4 + 3] : N_NODES;
            *(int4*)(row + s4) = qv;
        }
    }
}

// ---------------- fused layer: b128 gather -> MFMA MLP -> pool (+W1n) --------
// Gather: 8 edge-groups x 8 channels/lane; rows padded to 8 (was 32), loop
// processes 16 edges/iter (2 guarded 8-edge steps) -- ~39% fewer VMEM ops.
// MLPs on matrix cores: T[16][72] bf16 LDS, wave owns one 16-col tile, 2 mfma
// per matmul, frag-ordered weights. D: col=lane&15, row=4*(lane>>4)+i.
template <bool HAS_NEXT>
__global__ __launch_bounds__(256, 6)
void layer_fused(const bf16* __restrict__ ybf, const int* __restrict__ cnt,
                 const int* __restrict__ col, const int* __restrict__ batch,
                 const float* __restrict__ b1, const bf16* __restrict__ w2frag,
                 const float* __restrict__ b2, const bf16* __restrict__ w1nfrag,
                 bf16* __restrict__ ynext, float* __restrict__ pooled_l) {
    __shared__ float csh[4][8][65];               // group partials (stride 65: conflict-free)
    __shared__ __align__(16) short Tsh[16][72];   // t rows bf16, 144-B stride
    __shared__ __align__(16) short Hsh[16][72];   // h rows bf16
    const int wave = threadIdx.x >> 6, lane = threadIdx.x & 63;
    const int eg = lane >> 3;                     // edge group 0..7
    const int j  = lane & 7;                      // dword-quad index in row
    const uint32 joff = (uint32)j * 16u;
    const int nA = blockIdx.x * 16;               // 6250 blocks
    const int nW = nA + wave * 4;                 // this wave's first node
    const char* ybase = (const char*)ybf;

    // ---- phase 1: gather + t = relu(y_self + b1 + agg) for 4 nodes ----
    #pragma unroll
    for (int r = 0; r < 4; r++) {
        const int n = __builtin_amdgcn_readfirstlane(nW + r);
        const int deg8 = __builtin_amdgcn_readfirstlane((cnt[n] + 7) & ~7);
        const int s = n * CAP;                    // < 6.4M, fits int
        float acc[8] = {0.f, 0.f, 0.f, 0.f, 0.f, 0.f, 0.f, 0.f};
        for (int i = 0; i < deg8; i += 16) {
            int c0 = col[s + i + eg];             // 8-lane broadcast vector load
            uint4 p0 = *(const uint4*)(ybase + (((uint32)c0 << 7) + joff));
            const bool two = (i + 8) < deg8;      // wave-uniform guard
            uint4 p1;
            if (two) {
                int c1 = col[s + i + 8 + eg];
                p1 = *(const uint4*)(ybase + (((uint32)c1 << 7) + joff));
            }
            f32x2 f0 = unpk2(p0.x); acc[0] += f0.x; acc[1] += f0.y;
            f32x2 f1 = unpk2(p0.y); acc[2] += f1.x; acc[3] += f1.y;
            f32x2 f2 = unpk2(p0.z); acc[4] += f2.x; acc[5] += f2.y;
            f32x2 f3 = unpk2(p0.w); acc[6] += f3.x; acc[7] += f3.y;
            if (two) {
                f32x2 g0 = unpk2(p1.x); acc[0] += g0.x; acc[1] += g0.y;
                f32x2 g1 = unpk2(p1.y); acc[2] += g1.x; acc[3] += g1.y;
                f32x2 g2 = unpk2(p1.z); acc[4] += g2.x; acc[5] += g2.y;
                f32x2 g3 = unpk2(p1.w); acc[6] += g3.x; acc[7] += g3.y;
            }
        }
        #pragma unroll
        for (int d = 0; d < 8; d++) csh[wave][eg][8 * j + d] = acc[d];
        // per-wave LDS slice: lockstep + compiler lgkmcnt; no barrier
        float sumv = 0.f;
        #pragma unroll
        for (int ee = 0; ee < 8; ee++) sumv += csh[wave][ee][lane];
        float tv = bf2f(ybf[(long)n * 64 + lane]) + b1[lane] + sumv;
        Tsh[4 * wave + r][lane] = f2bs(fmaxf(tv, 0.f));
    }
    __syncthreads();                              // T complete (A spans all 16 rows)

    // ---- phase 2: H = relu(T @ W2 + b2), 2x mfma_f32_16x16x32_bf16 ----
    const int c15 = lane & 15, g16 = lane >> 4;
    s16x8 a0 = *(const s16x8*)((const char*)Tsh + c15 * 144 + g16 * 16);
    s16x8 a1 = *(const s16x8*)((const char*)Tsh + c15 * 144 + g16 * 16 + 64);
    const s16x8* w2q = (const s16x8*)w2frag;
    f32x4 hacc = {0.f, 0.f, 0.f, 0.f};
    hacc = __builtin_amdgcn_mfma_f32_16x16x32_bf16(a0, w2q[(wave * 2 + 0) * 64 + lane], hacc, 0, 0, 0);
    hacc = __builtin_amdgcn_mfma_f32_16x16x32_bf16(a1, w2q[(wave * 2 + 1) * 64 + lane], hacc, 0, 0, 0);
    const float bb = b2[16 * wave + c15];
    float hv[4];
    #pragma unroll
    for (int i = 0; i < 4; i++) hv[i] = fmaxf(hacc[i] + bb, 0.f);

    // ---- phase 3: Y = H @ W1n (no bias), same MFMA structure ----
    if (HAS_NEXT) {
        #pragma unroll
        for (int i = 0; i < 4; i++)                // lane holds H[4*g16+i][16w+c15]
            Hsh[4 * g16 + i][16 * wave + c15] = f2bs(hv[i]);
        __syncthreads();                           // H complete
        s16x8 h0 = *(const s16x8*)((const char*)Hsh + c15 * 144 + g16 * 16);
        s16x8 h1 = *(const s16x8*)((const char*)Hsh + c15 * 144 + g16 * 16 + 64);
        const s16x8* w1q = (const s16x8*)w1nfrag;
        f32x4 yac = {0.f, 0.f, 0.f, 0.f};
        yac = __builtin_amdgcn_mfma_f32_16x16x32_bf16(h0, w1q[(wave * 2 + 0) * 64 + lane], yac, 0, 0, 0);
        yac = __builtin_amdgcn_mfma_f32_16x16x32_bf16(h1, w1q[(wave * 2 + 1) * 64 + lane], yac, 0, 0, 0);
        #pragma unroll
        for (int i = 0; i < 4; i++)
            ynext[(long)(nA + 4 * g16 + i) * 64 + 16 * wave + c15] = __float2bfloat16(yac[i]);
    }

    // ---- pooling from D-layout regs: shfl_xor over the 4 row-groups ----
    const int gA = __builtin_amdgcn_readfirstlane(batch[nA]);
    const int gZ = __builtin_amdgcn_readfirstlane(batch[nA + 15]);
    float* rep = pooled_l + (long)(blockIdx.x & (NREP - 1)) * NUM_GRAPHS * HID;
    if (gA == gZ) {               // ~98% of blocks: whole block same graph
        float ps = (hv[0] + hv[1]) + (hv[2] + hv[3]);
        ps += __shfl_xor(ps, 32);
        ps += __shfl_xor(ps, 16);
        if (g16 == 0)             // lanes 0-15: full col sums for this wave's tile
            atomicAdd(&rep[gA * 64 + 16 * wave + c15], ps);
    } else {                      // graph boundary inside block: per-node atomics
        #pragma unroll
        for (int i = 0; i < 4; i++) {
            int gb = batch[nA + 4 * g16 + i];
            atomicAdd(&rep[gb * 64 + 16 * wave + c15], hv[i]);
        }
    }
}

// ---------------- JK proj + classifier Linear1 + BN-stat atomics -------------
__global__ void jk_cls1(const float* __restrict__ pooled, const int* __restrict__ cntg,
                        const float* __restrict__ Wjk, const float* __restrict__ bjk,
                        const float* __restrict__ Wc1, const float* __restrict__ bc1,
                        float* __restrict__ Z, float* __restrict__ zstats) {
    __shared__ __align__(16) float sh[4][HID];    // per-layer summed pooled rows
    __shared__ float pacc[4][HID];                // per-wave partial pjk
    __shared__ __align__(16) float pj[HID];       // full pjk row
    __shared__ float zacc[4][HID];                // per-wave partial Z
    const int g = blockIdx.x;                     // 128 blocks
    const int wave = threadIdx.x >> 6, j = threadIdx.x & 63;

    // stage 1: wave w = layer w. Sum NREP replicas, then partial JK matmul.
    float s = 0.f;
    for (int r = 0; r < NREP; r++)
        s += pooled[((long)(wave * NREP + r) * NUM_GRAPHS + g) * 64 + j];
    sh[wave][j] = s;                              // own-wave slice: lockstep, no barrier
    const float* W = Wjk + (long)wave * HID * 64;
    float a = 0.f;
    for (int k = 0; k < 64; k += 4) {
        f32x4 sv = *(const f32x4*)&sh[wave][k];
        a += sv.x * W[(k + 0) * 64 + j];
        a += sv.y * W[(k + 1) * 64 + j];
        a += sv.z * W[(k + 2) * 64 + j];
        a += sv.w * W[(k + 3) * 64 + j];
    }
    pacc[wave][j] = a;
    __syncthreads();

    // full pjk row (every thread computes same value for its j)
    if (wave == 0)
        pj[j] = (float)cntg[g] * bjk[j]
              + (pacc[0][j] + pacc[1][j]) + (pacc[2][j] + pacc[3][j]);
    __syncthreads();

    // stage 2: wave w handles k in [16w, 16w+16) of Z = pjk @ Wc1
    float z = 0.f;
    for (int k = 16 * wave; k < 16 * wave + 16; k += 4) {
        f32x4 pv = *(const f32x4*)&pj[k];
        z += pv.x * Wc1[(k + 0) * 64 + j];
        z += pv.y * Wc1[(k + 1) * 64 + j];
        z += pv.z * Wc1[(k + 2) * 64 + j];
        z += pv.w * Wc1[(k + 3) * 64 + j];
    }
    zacc[wave][j] = z;
    __syncthreads();
    if (wave == 0) {
        float zv = bc1[j] + (zacc[0][j] + zacc[1][j]) + (zacc[2][j] + zacc[3][j]);
        Z[g * 64 + j] = zv;
        atomicAdd(&zstats[j], zv);
        atomicAdd(&zstats[HID + j], zv * zv);
    }
}

// ---------------- classifier tail: BN(batch stats) -> ReLU -> Linear ---------
__global__ void cls2(const float* __restrict__ Z, const float* __restrict__ zstats,
                     const float* __restrict__ gamma, const float* __restrict__ beta,
                     const float* __restrict__ Wc2, const float* __restrict__ bc2,
                     float* __restrict__ out) {
    __shared__ float v[HID];
    const int g = blockIdx.x, j = threadIdx.x;    // 128 blocks x 64 threads
    float mu = zstats[j] * (1.f / NUM_GRAPHS);
    float var = zstats[HID + j] * (1.f / NUM_GRAPHS) - mu * mu;
    float rs = rsqrtf(var + BN_EPS);
    float zv = Z[g * 64 + j];
    v[j] = fmaxf(gamma[j] * (zv - mu) * rs + beta[j], 0.f);
    // single wave: lockstep + compiler lgkmcnt; no barrier
    if (j < OUT_CH) {
        float acc = bc2[j];
        for (int k = 0; k < 64; k++) acc += v[k] * Wc2[k * OUT_CH + j];
        out[g * OUT_CH + j] = acc;
    }
}

// -----------------------------------------------------------------------------
extern "C" void kernel_launch(void* const* d_in, const int* in_sizes, int n_in,
                              void* d_out, int out_size, void* d_ws, size_t ws_size,
                              hipStream_t stream) {
    const float* x     = (const float*)d_in[0];
    const int*   ei    = (const int*)d_in[1];
    const int*   batch = (const int*)d_in[2];
    const float* W1f   = (const float*)d_in[3];
    const float* b1f   = (const float*)d_in[4];
    const float* W2f   = (const float*)d_in[5];
    const float* b2f   = (const float*)d_in[6];
    const float* W1r   = (const float*)d_in[7];
    const float* b1r   = (const float*)d_in[8];
    const float* W2r   = (const float*)d_in[9];
    const float* b2r   = (const float*)d_in[10];
    const float* Wjk   = (const float*)d_in[11];
    const float* bjk   = (const float*)d_in[12];
    const float* Wc1   = (const float*)d_in[13];
    const float* bc1   = (const float*)d_in[14];
    const float* gamma = (const float*)d_in[15];
    const float* beta  = (const float*)d_in[16];
    const float* Wc2   = (const float*)d_in[17];
    const float* bc2   = (const float*)d_in[18];

    const int* src = ei;
    const int* dst = ei + N_EDGES;

    // workspace layout (all segments 8-B aligned). ghist sits OUTSIDE the
    // zeroed span (stage1 zeroes concurrently with bhist atomics on ghist).
    float* ws        = (float*)d_ws;
    float* Z         = ws;                                      // 8192 floats (cls Z)
    bf16*  ybfA      = (bf16*)(Z + NUM_GRAPHS * HID);           // (N+1)*64 bf16
    bf16*  ybfB      = ybfA + (long)(N_NODES + 1) * HID;        // (N+1)*64 bf16
    int*   cnt       = (int*)(ybfB + (long)(N_NODES + 1) * HID);// 100000 (written by bfill)
    float* pooled    = (float*)(cnt + N_NODES);                 // 4*8*8192 floats
    int*   gcursor   = (int*)(pooled + (long)N_LAYERS * NREP * NUM_GRAPHS * HID); // 256
    int*   gbase     = gcursor + NBKT;                          // 256
    int*   cntg      = gbase + NBKT;                            // 128
    float* zstats    = (float*)(cntg + NUM_GRAPHS);             // 128 (sum | sumsq)
    int*   ghist     = (int*)(zstats + 2 * HID);                // 256 (zeroed in prep)
    int*   col       = ghist + NBKT;                            // 6.4M ints
    int*   epart     = col + (long)N_NODES * CAP;               // 1.6M packed ints
    bf16*  wfrag     = (bf16*)(epart + N_EDGES);                // 7*4096 + 8192 bf16
    // zeroed span: pooled .. zstats (gcursor/gbase/cntg rewritten by bscan)
    const int ZN = N_LAYERS * NREP * NUM_GRAPHS * HID
                 + 2 * NBKT + NUM_GRAPHS + 2 * HID;

    // ---- prep: ghist zero + all weight fragments (before stage1 reads) ----
    prep<<<1 + NWMAT, 256, 0, stream>>>(ghist, W1f, W2f, W2r, W1r, wfrag);

    // ---- stage1: bhist | zero | proj0-MFMA fused (all independent) ----
    stage1<<<PNB + ZB + P0B, 256, 0, stream>>>(
        dst, ghist, (int*)pooled, ZN, x, wfrag + 7 * HID * HID, ybfA);
    bscan<<<1, 256, 0, stream>>>(ghist, gcursor, gbase, batch, cntg, ybfA, ybfB);
    bpart<<<PNB, 256, 0, stream>>>(src, dst, gcursor, epart);
    bfill<<<NBUCK * 4, 256, 0, stream>>>(epart, gbase, ghist, cnt, col);

    // ---- 4 fused layers (16 nodes per block; MFMA MLP) ----
    const int NB = N_NODES / 16;                                // 6250
    const long PL = (long)NREP * NUM_GRAPHS * HID;
    const int WM = HID * HID;                                   // 4096 elems / matrix
    layer_fused<true><<<NB, 256, 0, stream>>>(
        ybfA, cnt, col, batch, b1f, wfrag + 0 * WM, b2f,
        wfrag + 4 * WM, ybfB, pooled);
    layer_fused<true><<<NB, 256, 0, stream>>>(
        ybfB, cnt, col, batch, b1r, wfrag + 1 * WM, b2r,
        wfrag + 5 * WM, ybfA, pooled + 1 * PL);
    layer_fused<true><<<NB, 256, 0, stream>>>(
        ybfA, cnt, col, batch, b1r + HID, wfrag + 2 * WM, b2r + HID,
        wfrag + 6 * WM, ybfB, pooled + 2 * PL);
    layer_fused<false><<<NB, 256, 0, stream>>>(
        ybfB, cnt, col, batch, b1r + 2 * HID, wfrag + 3 * WM, b2r + 2 * HID,
        nullptr, nullptr, pooled + 3 * PL);

    // ---- JK + classifier: wide tail (128 blocks each) ----
    jk_cls1<<<NUM_GRAPHS, 256, 0, stream>>>(pooled, cntg, Wjk, bjk, Wc1, bc1,
                                            Z, zstats);
    cls2<<<NUM_GRAPHS, 64, 0, stream>>>(Z, zstats, gamma, beta, Wc2, bc2,
                                        (float*)d_out);
}

// Round 12
// 362.287 us; speedup vs baseline: 1.0544x; 1.0544x over previous
//
#include <hip/hip_runtime.h>
#include <hip/hip_bf16.h>

#define N_NODES    100000
#define N_EDGES    1600000
#define IN_CH      128
#define HID        64
#define N_LAYERS   4
#define OUT_CH     10
#define NUM_GRAPHS 128
#define BN_EPS     1e-5f
#define CAP        64             // padded CSR row capacity; P(deg>64) ~ 1e-19 at Poisson(16)
#define NREP       8              // pooled replicas (cuts per-address atomic chains 8x)
#define NBKT       256            // dst>>9 -> buckets 0..195 (256 slots for pow2 LDS)
#define NBUCK      196            // ceil(100000 / 512) actual buckets
#define EPB        2048           // edges per block in partition kernels
#define PNB        782            // ceil(1.6M / 2048)
#define SUBCAP     2688           // per-128-node-slice edge capacity (mean 2048, sd 45: 14 sigma)
#define ZB         360            // zero blocks inside stage1
#define P0B        6250           // proj0 blocks inside stage1
#define NWMAT      8              // fragment matrices: 4 W2 + 3 W1n + W1f(K=128)

typedef __hip_bfloat16 bf16;
typedef unsigned int uint32;
typedef float f32x2 __attribute__((ext_vector_type(2)));
typedef float f32x4 __attribute__((ext_vector_type(4)));
typedef short s16x8 __attribute__((ext_vector_type(8)));   // 8 bf16 (4 VGPRs)

__device__ __forceinline__ float bf2f(bf16 v) { return __bfloat162float(v); }
// unpack packed bf16x2 dword -> f32x2 pair (bf16 -> f32 is <<16)
__device__ __forceinline__ f32x2 unpk2(uint32 p) {
    f32x2 r;
    r.x = __uint_as_float(p << 16);
    r.y = __uint_as_float(p & 0xffff0000u);
    return r;
}
__device__ __forceinline__ short f2bs(float f) {
    bf16 b = __float2bfloat16(f);
    return *reinterpret_cast<short*>(&b);
}

// ---------------- prep: ghist zero + weight fragment conversion --------------
// block 0: zero ghist. blocks 1..8: convert one weight matrix to MFMA B-frag
// order (bf16). mi 0..6: 64x64 (4 W2, 3 W1n), K=64 (2 k-slices x 4 tiles).
// mi 7: W1f 128x64, K=128 (4 k-slices x 4 tiles). Runs BEFORE stage1 because
// stage1's proj0 blocks consume the W1f fragments (no same-kernel ordering).
__global__ void prep(int* __restrict__ ghist,
                     const float* __restrict__ W1f, const float* __restrict__ W2f,
                     const float* __restrict__ W2r, const float* __restrict__ W1r,
                     bf16* __restrict__ wfrag) {
    const int bid = blockIdx.x, t = threadIdx.x;  // 9 blocks x 256 threads
    if (bid == 0) { ghist[t] = 0; return; }
    const int mi = bid - 1;                       // 0..7
    if (mi < 7) {
        const float* W = (mi == 0) ? W2f
                       : (mi <= 3) ? W2r + (long)(mi - 1) * HID * HID
                                   : W1r + (long)(mi - 4) * HID * HID;
        bf16* out = wfrag + mi * HID * HID;
        for (int u = 0; u < 2; u++) {
            int idx = u * 256 + t;                // (tile*2+ks)*64 + lane
            int lane = idx & 63, tk = idx >> 6;
            int kbase = (tk & 1) * 32 + 8 * (lane >> 4);
            int c = (tk >> 1) * 16 + (lane & 15);
            #pragma unroll
            for (int j = 0; j < 8; j++)
                out[idx * 8 + j] = __float2bfloat16(W[(kbase + j) * 64 + c]);
        }
    } else {
        bf16* out = wfrag + 7 * HID * HID;        // W1f: 1024 frag groups
        for (int u = 0; u < 4; u++) {
            int idx = u * 256 + t;                // (tile*4+ks)*64 + lane
            int lane = idx & 63, tk = idx >> 6;   // 0..15
            int kbase = (tk & 3) * 32 + 8 * (lane >> 4);
            int c = (tk >> 2) * 16 + (lane & 15);
            #pragma unroll
            for (int j = 0; j < 8; j++)
                out[idx * 8 + j] = __float2bfloat16(W1f[(kbase + j) * 64 + c]);
        }
    }
}

// ---------------- stage1: fused bhist | zero | proj0(MFMA) -------------------
// blocks [0,782): edge-bucket histogram; [782,1142): zero accum region;
// [1142,7392): layer-0 projection ybf = bf16(x @ W1f) on matrix cores:
// 16 nodes/block, x cast to bf16 in LDS, 4 mfma_16x16x32 per wave (K=128).
__global__ void stage1(const int* __restrict__ dst, int* __restrict__ ghist,
                       int* __restrict__ zp, int zn,
                       const float* __restrict__ x, const bf16* __restrict__ w1ffrag,
                       bf16* __restrict__ ybf) {
    const int bid = blockIdx.x;
    const int t = threadIdx.x;
    if (bid < PNB) {
        // ---- bhist ----
        __shared__ int h[NBKT];
        h[t] = 0;
        __syncthreads();
        long base = (long)bid * EPB;
        for (int u = 0; u < 8; u++) {
            long e = base + u * 256 + t;
            if (e < N_EDGES) atomicAdd(&h[dst[e] >> 9], 1);
        }
        __syncthreads();
        if (h[t]) atomicAdd(&ghist[t], h[t]);
    } else if (bid < PNB + ZB) {
        // ---- zero accumulators (pooled .. zstats; ghist excluded) ----
        int i = (bid - PNB) * 256 + t;
        const int st = ZB * 256;
        for (; i < zn; i += st) zp[i] = 0;
    } else {
        // ---- proj0 via MFMA: 16 nodes per block ----
        __shared__ __align__(16) short Xsh[16][136];  // 4352 B; 272-B row stride
        const int wave = t >> 6, lane = t & 63;
        const int nb = (bid - PNB - ZB) * 16;         // 6250*16 == 100000
        {   // stage x -> bf16 LDS: thread = (row: t>>4, cols: 8*(t&15)..+8)
            int row = t >> 4, c0 = (t & 15) * 8;
            const float* xr = x + (long)(nb + row) * IN_CH + c0;
            f32x4 v0 = *(const f32x4*)(xr);
            f32x4 v1 = *(const f32x4*)(xr + 4);
            s16x8 b;
            b[0] = f2bs(v0.x); b[1] = f2bs(v0.y); b[2] = f2bs(v0.z); b[3] = f2bs(v0.w);
            b[4] = f2bs(v1.x); b[5] = f2bs(v1.y); b[6] = f2bs(v1.z); b[7] = f2bs(v1.w);
            *(s16x8*)&Xsh[row][c0] = b;
        }
        __syncthreads();
        const int c15 = lane & 15, g16 = lane >> 4;
        const s16x8* wq = (const s16x8*)w1ffrag;
        f32x4 yac = {0.f, 0.f, 0.f, 0.f};
        #pragma unroll
        for (int ks = 0; ks < 4; ks++) {
            s16x8 a = *(const s16x8*)((const char*)Xsh + c15 * 272 + ks * 64 + g16 * 16);
            yac = __builtin_amdgcn_mfma_f32_16x16x32_bf16(
                a, wq[(wave * 4 + ks) * 64 + lane], yac, 0, 0, 0);
        }
        #pragma unroll
        for (int i = 0; i < 4; i++)               // D: col=lane&15, row=4*(lane>>4)+i
            ybf[(long)(nb + 4 * g16 + i) * 64 + 16 * wave + c15] = __float2bfloat16(yac[i]);
    }
}

// ---------------- bucket scan + cntg (binary search) + ybf pad-row zero ------
__global__ void bscan(const int* __restrict__ ghist, int* __restrict__ gcursor,
                      int* __restrict__ gbase,
                      const int* __restrict__ batch, int* __restrict__ cntg,
                      bf16* __restrict__ ybfA, bf16* __restrict__ ybfB) {
    __shared__ int sh[NBKT];
    int t = threadIdx.x;                          // 256 threads
    int v = ghist[t];
    sh[t] = v;
    __syncthreads();
    for (int off = 1; off < NBKT; off <<= 1) {
        int a = (t >= off) ? sh[t - off] : 0;
        __syncthreads();
        sh[t] += a;
        __syncthreads();
    }
    gcursor[t] = sh[t] - v;                       // exclusive bucket base (bpart cursor)
    gbase[t]   = sh[t] - v;                       // immutable copy for bfill
    if (t < NUM_GRAPHS) {                         // per-graph node counts
        int g = t, lo = 0, hi = N_NODES;
        while (lo < hi) { int m = (lo + hi) >> 1; if (batch[m] < g) lo = m + 1; else hi = m; }
        int lb = lo;
        lo = 0; hi = N_NODES;
        while (lo < hi) { int m = (lo + hi) >> 1; if (batch[m] < g + 1) lo = m + 1; else hi = m; }
        cntg[g] = lo - lb;
    }
    if (t < HID) {                                // sentinel zero-row for tail-free gather
        ybfA[(long)N_NODES * HID + t] = __float2bfloat16(0.f);
        ybfB[(long)N_NODES * HID + t] = __float2bfloat16(0.f);
    }
}

// ---------------- partition edges into bucket order (packed 4-B records) -----
// record = src | (dst&511)<<17  (src < 2^17, local dst < 2^9)
__global__ void bpart(const int* __restrict__ src, const int* __restrict__ dst,
                      int* __restrict__ gcursor, int* __restrict__ epart) {
    __shared__ int h[NBKT];
    __shared__ int cur[NBKT];
    int t = threadIdx.x;
    h[t] = 0;
    __syncthreads();
    long base = (long)blockIdx.x * EPB;
    int myd[8], mys[8];
    for (int u = 0; u < 8; u++) {
        long e = base + u * 256 + t;
        if (e < N_EDGES) {
            myd[u] = dst[e];
            mys[u] = src[e];
            atomicAdd(&h[myd[u] >> 9], 1);
        } else myd[u] = -1;
    }
    __syncthreads();
    if (h[t]) cur[t] = atomicAdd(&gcursor[t], h[t]);
    __syncthreads();
    for (int u = 0; u < 8; u++) {
        if (myd[u] >= 0) {
            int pos = atomicAdd(&cur[myd[u] >> 9], 1);
            epart[pos] = mys[u] | ((myd[u] & 511) << 17);
        }
    }
}

// ---------------- per-slice LDS counting sort -> coalesced CSR fill ----------
// Rows padded to a multiple of 32, MINIMUM 32 (even deg-0 rows get a full
// sentinel chunk) so the gather's first 32-edge chunk is unconditionally
// valid -- enables the batched-ILP gather (round-11 lesson: latency-bound,
// not issue-bound; deg8 padding destroyed load pipelining and regressed).
__global__ __launch_bounds__(256)
void bfill(const int* __restrict__ epart, const int* __restrict__ gbase,
           const int* __restrict__ ghist, int* __restrict__ cnt,
           int* __restrict__ col) {
    __shared__ int lcnt[128];
    __shared__ int loff[128];
    __shared__ int lsrc[SUBCAP];
    const int b = blockIdx.x >> 2;                // 512-node bucket 0..195
    const int q = blockIdx.x & 3;                 // 128-node slice 0..3
    const int t = threadIdx.x;                    // 256 threads
    const int n0 = (b << 9) + (q << 7);
    if (n0 >= N_NODES) return;                    // uniform: whole block exits
    const int nN = min(128, N_NODES - n0);
    const int base = gbase[b];
    const int m = ghist[b];
    const int lo = q << 7;                        // local9 range [lo, lo+128)

    if (t < 128) lcnt[t] = 0;
    __syncthreads();
    // pass 1: per-node degree (slice filter)
    for (int e = t; e < m; e += 256) {
        int ln = (int)((uint32)epart[base + e] >> 17) - lo;
        if ((uint32)ln < 128u) atomicAdd(&lcnt[ln], 1);
    }
    __syncthreads();
    // inclusive Hillis-Steele scan over 128 counts
    if (t < 128) loff[t] = lcnt[t];
    __syncthreads();
    for (int off = 1; off < 128; off <<= 1) {
        int a = (t < 128 && t >= off) ? loff[t - off] : 0;
        __syncthreads();
        if (t < 128) loff[t] += a;
        __syncthreads();
    }
    int ex = 0;
    if (t < 128) ex = loff[t] - lcnt[t];          // exclusive offset
    __syncthreads();
    if (t < 128) { loff[t] = ex; lcnt[t] = 0; }   // lcnt reused as cursor
    __syncthreads();
    // pass 2: scatter srcs into per-node runs
    for (int e = t; e < m; e += 256) {
        uint32 v = (uint32)epart[base + e];
        int ln = (int)(v >> 17) - lo;
        if ((uint32)ln < 128u) {
            int slot = atomicAdd(&lcnt[ln], 1);
            lsrc[loff[ln] + slot] = (int)(v & 0x1FFFFu);
        }
    }
    __syncthreads();
    // write rows: data + sentinel pad to deg32 (min 32), int4 stores; plus cnt
    if (t < nN) {
        int deg = lcnt[t];
        int st  = loff[t];
        int n   = n0 + t;
        cnt[n] = deg;
        int d32 = (deg + 31) & ~31;
        if (d32 == 0) d32 = 32;                   // deg-0: full sentinel chunk
        int* row = col + n * CAP;
        for (int s4 = 0; s4 < d32; s4 += 4) {
            int4 qv;
            qv.x = (s4 + 0 < deg) ? lsrc[st + s4 + 0] : N_NODES;
            qv.y = (s4 + 1 < deg) ? lsrc[st + s4 + 1] : N_NODES;
            qv.z = (s4 + 2 < deg) ? lsrc[st + s4 + 2] : N_NODES;
            qv.w = (s4 + 3 < deg) ? lsrc[st + s4 + 3] : N_NODES;
            *(int4*)(row + s4) = qv;
        }
    }
}

// ---------------- fused layer: batched gather -> MFMA MLP -> pool (+W1n) -----
// Gather restructured for LATENCY (round-11 lesson): all 4 rows' first
// 32-edge chunks issue together -- 16 independent col loads, then 16
// independent dwordx4 y-loads, all outstanding at once (2 latency exposures
// per wave vs 8 when rows ran serially). Chunk 0 is always valid (bfill pads
// min 32). Tails (deg>32, P~1e-4) use the old per-chunk loop. MLPs on matrix
// cores: 2 mfma per matmul, frag-ordered weights. D: col=lane&15,
// row=4*(lane>>4)+i.
template <bool HAS_NEXT>
__global__ __launch_bounds__(256, 4)
void layer_fused(const bf16* __restrict__ ybf, const int* __restrict__ cnt,
                 const int* __restrict__ col, const int* __restrict__ batch,
                 const float* __restrict__ b1, const bf16* __restrict__ w2frag,
                 const float* __restrict__ b2, const bf16* __restrict__ w1nfrag,
                 bf16* __restrict__ ynext, float* __restrict__ pooled_l) {
    __shared__ float csh[4][8][65];               // group partials (stride 65: conflict-free)
    __shared__ __align__(16) short Tsh[16][72];   // t rows bf16, 144-B stride
    __shared__ __align__(16) short Hsh[16][72];   // h rows bf16
    const int wave = threadIdx.x >> 6, lane = threadIdx.x & 63;
    const int eg = lane >> 3;                     // edge group 0..7
    const int j  = lane & 7;                      // dword-quad index in row
    const uint32 joff = (uint32)j * 16u;
    const int nA = blockIdx.x * 16;               // 6250 blocks
    const int nW = nA + wave * 4;                 // this wave's first node
    const char* ybase = (const char*)ybf;

    // ---- phase 1: batched gather + t = relu(y_self + b1 + agg), 4 rows ----
    int s_[4], d_[4];
    #pragma unroll
    for (int r = 0; r < 4; r++) {
        const int n = __builtin_amdgcn_readfirstlane(nW + r);
        d_[r] = __builtin_amdgcn_readfirstlane((cnt[n] + 31) & ~31);
        s_[r] = n * CAP;                          // < 6.4M, fits int
    }
    int c_[4][4];
    #pragma unroll
    for (int r = 0; r < 4; r++)
        #pragma unroll
        for (int t = 0; t < 4; t++)
            c_[r][t] = col[s_[r] + 8 * t + eg];   // 16 independent col loads
    uint4 p_[4][4];
    #pragma unroll
    for (int r = 0; r < 4; r++)
        #pragma unroll
        for (int t = 0; t < 4; t++)               // 16 independent y loads
            p_[r][t] = *(const uint4*)(ybase + (((uint32)c_[r][t] << 7) + joff));

    #pragma unroll
    for (int r = 0; r < 4; r++) {
        float acc[8] = {0.f, 0.f, 0.f, 0.f, 0.f, 0.f, 0.f, 0.f};
        #pragma unroll
        for (int t = 0; t < 4; t++) {
            f32x2 f0 = unpk2(p_[r][t].x); acc[0] += f0.x; acc[1] += f0.y;
            f32x2 f1 = unpk2(p_[r][t].y); acc[2] += f1.x; acc[3] += f1.y;
            f32x2 f2 = unpk2(p_[r][t].z); acc[4] += f2.x; acc[5] += f2.y;
            f32x2 f3 = unpk2(p_[r][t].w); acc[6] += f3.x; acc[7] += f3.y;
        }
        for (int i = 32; i < d_[r]; i += 32) {    // rare tail (P ~ 1e-4)
            uint4 q[4];
            #pragma unroll
            for (int t = 0; t < 4; t++) {
                int c = col[s_[r] + i + 8 * t + eg];
                q[t] = *(const uint4*)(ybase + (((uint32)c << 7) + joff));
            }
            #pragma unroll
            for (int t = 0; t < 4; t++) {
                f32x2 f0 = unpk2(q[t].x); acc[0] += f0.x; acc[1] += f0.y;
                f32x2 f1 = unpk2(q[t].y); acc[2] += f1.x; acc[3] += f1.y;
                f32x2 f2 = unpk2(q[t].z); acc[4] += f2.x; acc[5] += f2.y;
                f32x2 f3 = unpk2(q[t].w); acc[6] += f3.x; acc[7] += f3.y;
            }
        }
        #pragma unroll
        for (int d = 0; d < 8; d++) csh[wave][eg][8 * j + d] = acc[d];
        // per-wave LDS slice: lockstep + compiler lgkmcnt; no barrier
        float sumv = 0.f;
        #pragma unroll
        for (int ee = 0; ee < 8; ee++) sumv += csh[wave][ee][lane];
        const int n = __builtin_amdgcn_readfirstlane(nW + r);
        float tv = bf2f(ybf[(long)n * 64 + lane]) + b1[lane] + sumv;
        Tsh[4 * wave + r][lane] = f2bs(fmaxf(tv, 0.f));
    }
    __syncthreads();                              // T complete (A spans all 16 rows)

    // ---- phase 2: H = relu(T @ W2 + b2), 2x mfma_f32_16x16x32_bf16 ----
    const int c15 = lane & 15, g16 = lane >> 4;
    s16x8 a0 = *(const s16x8*)((const char*)Tsh + c15 * 144 + g16 * 16);
    s16x8 a1 = *(const s16x8*)((const char*)Tsh + c15 * 144 + g16 * 16 + 64);
    const s16x8* w2q = (const s16x8*)w2frag;
    f32x4 hacc = {0.f, 0.f, 0.f, 0.f};
    hacc = __builtin_amdgcn_mfma_f32_16x16x32_bf16(a0, w2q[(wave * 2 + 0) * 64 + lane], hacc, 0, 0, 0);
    hacc = __builtin_amdgcn_mfma_f32_16x16x32_bf16(a1, w2q[(wave * 2 + 1) * 64 + lane], hacc, 0, 0, 0);
    const float bb = b2[16 * wave + c15];
    float hv[4];
    #pragma unroll
    for (int i = 0; i < 4; i++) hv[i] = fmaxf(hacc[i] + bb, 0.f);

    // ---- phase 3: Y = H @ W1n (no bias), same MFMA structure ----
    if (HAS_NEXT) {
        #pragma unroll
        for (int i = 0; i < 4; i++)                // lane holds H[4*g16+i][16w+c15]
            Hsh[4 * g16 + i][16 * wave + c15] = f2bs(hv[i]);
        __syncthreads();                           // H complete
        s16x8 h0 = *(const s16x8*)((const char*)Hsh + c15 * 144 + g16 * 16);
        s16x8 h1 = *(const s16x8*)((const char*)Hsh + c15 * 144 + g16 * 16 + 64);
        const s16x8* w1q = (const s16x8*)w1nfrag;
        f32x4 yac = {0.f, 0.f, 0.f, 0.f};
        yac = __builtin_amdgcn_mfma_f32_16x16x32_bf16(h0, w1q[(wave * 2 + 0) * 64 + lane], yac, 0, 0, 0);
        yac = __builtin_amdgcn_mfma_f32_16x16x32_bf16(h1, w1q[(wave * 2 + 1) * 64 + lane], yac, 0, 0, 0);
        #pragma unroll
        for (int i = 0; i < 4; i++)
            ynext[(long)(nA + 4 * g16 + i) * 64 + 16 * wave + c15] = __float2bfloat16(yac[i]);
    }

    // ---- pooling from D-layout regs: shfl_xor over the 4 row-groups ----
    const int gA = __builtin_amdgcn_readfirstlane(batch[nA]);
    const int gZ = __builtin_amdgcn_readfirstlane(batch[nA + 15]);
    float* rep = pooled_l + (long)(blockIdx.x & (NREP - 1)) * NUM_GRAPHS * HID;
    if (gA == gZ) {               // ~98% of blocks: whole block same graph
        float ps = (hv[0] + hv[1]) + (hv[2] + hv[3]);
        ps += __shfl_xor(ps, 32);
        ps += __shfl_xor(ps, 16);
        if (g16 == 0)             // lanes 0-15: full col sums for this wave's tile
            atomicAdd(&rep[gA * 64 + 16 * wave + c15], ps);
    } else {                      // graph boundary inside block: per-node atomics
        #pragma unroll
        for (int i = 0; i < 4; i++) {
            int gb = batch[nA + 4 * g16 + i];
            atomicAdd(&rep[gb * 64 + 16 * wave + c15], hv[i]);
        }
    }
}

// ---------------- JK proj + classifier Linear1 + BN-stat atomics -------------
__global__ void jk_cls1(const float* __restrict__ pooled, const int* __restrict__ cntg,
                        const float* __restrict__ Wjk, const float* __restrict__ bjk,
                        const float* __restrict__ Wc1, const float* __restrict__ bc1,
                        float* __restrict__ Z, float* __restrict__ zstats) {
    __shared__ __align__(16) float sh[4][HID];    // per-layer summed pooled rows
    __shared__ float pacc[4][HID];                // per-wave partial pjk
    __shared__ __align__(16) float pj[HID];       // full pjk row
    __shared__ float zacc[4][HID];                // per-wave partial Z
    const int g = blockIdx.x;                     // 128 blocks
    const int wave = threadIdx.x >> 6, j = threadIdx.x & 63;

    // stage 1: wave w = layer w. Sum NREP replicas, then partial JK matmul.
    float s = 0.f;
    for (int r = 0; r < NREP; r++)
        s += pooled[((long)(wave * NREP + r) * NUM_GRAPHS + g) * 64 + j];
    sh[wave][j] = s;                              // own-wave slice: lockstep, no barrier
    const float* W = Wjk + (long)wave * HID * 64;
    float a = 0.f;
    for (int k = 0; k < 64; k += 4) {
        f32x4 sv = *(const f32x4*)&sh[wave][k];
        a += sv.x * W[(k + 0) * 64 + j];
        a += sv.y * W[(k + 1) * 64 + j];
        a += sv.z * W[(k + 2) * 64 + j];
        a += sv.w * W[(k + 3) * 64 + j];
    }
    pacc[wave][j] = a;
    __syncthreads();

    // full pjk row (every thread computes same value for its j)
    if (wave == 0)
        pj[j] = (float)cntg[g] * bjk[j]
              + (pacc[0][j] + pacc[1][j]) + (pacc[2][j] + pacc[3][j]);
    __syncthreads();

    // stage 2: wave w handles k in [16w, 16w+16) of Z = pjk @ Wc1
    float z = 0.f;
    for (int k = 16 * wave; k < 16 * wave + 16; k += 4) {
        f32x4 pv = *(const f32x4*)&pj[k];
        z += pv.x * Wc1[(k + 0) * 64 + j];
        z += pv.y * Wc1[(k + 1) * 64 + j];
        z += pv.z * Wc1[(k + 2) * 64 + j];
        z += pv.w * Wc1[(k + 3) * 64 + j];
    }
    zacc[wave][j] = z;
    __syncthreads();
    if (wave == 0) {
        float zv = bc1[j] + (zacc[0][j] + zacc[1][j]) + (zacc[2][j] + zacc[3][j]);
        Z[g * 64 + j] = zv;
        atomicAdd(&zstats[j], zv);
        atomicAdd(&zstats[HID + j], zv * zv);
    }
}

// ---------------- classifier tail: BN(batch stats) -> ReLU -> Linear ---------
__global__ void cls2(const float* __restrict__ Z, const float* __restrict__ zstats,
                     const float* __restrict__ gamma, const float* __restrict__ beta,
                     const float* __restrict__ Wc2, const float* __restrict__ bc2,
                     float* __restrict__ out) {
    __shared__ float v[HID];
    const int g = blockIdx.x, j = threadIdx.x;    // 128 blocks x 64 threads
    float mu = zstats[j] * (1.f / NUM_GRAPHS);
    float var = zstats[HID + j] * (1.f / NUM_GRAPHS) - mu * mu;
    float rs = rsqrtf(var + BN_EPS);
    float zv = Z[g * 64 + j];
    v[j] = fmaxf(gamma[j] * (zv - mu) * rs + beta[j], 0.f);
    // single wave: lockstep + compiler lgkmcnt; no barrier
    if (j < OUT_CH) {
        float acc = bc2[j];
        for (int k = 0; k < 64; k++) acc += v[k] * Wc2[k * OUT_CH + j];
        out[g * OUT_CH + j] = acc;
    }
}

// -----------------------------------------------------------------------------
extern "C" void kernel_launch(void* const* d_in, const int* in_sizes, int n_in,
                              void* d_out, int out_size, void* d_ws, size_t ws_size,
                              hipStream_t stream) {
    const float* x     = (const float*)d_in[0];
    const int*   ei    = (const int*)d_in[1];
    const int*   batch = (const int*)d_in[2];
    const float* W1f   = (const float*)d_in[3];
    const float* b1f   = (const float*)d_in[4];
    const float* W2f   = (const float*)d_in[5];
    const float* b2f   = (const float*)d_in[6];
    const float* W1r   = (const float*)d_in[7];
    const float* b1r   = (const float*)d_in[8];
    const float* W2r   = (const float*)d_in[9];
    const float* b2r   = (const float*)d_in[10];
    const float* Wjk   = (const float*)d_in[11];
    const float* bjk   = (const float*)d_in[12];
    const float* Wc1   = (const float*)d_in[13];
    const float* bc1   = (const float*)d_in[14];
    const float* gamma = (const float*)d_in[15];
    const float* beta  = (const float*)d_in[16];
    const float* Wc2   = (const float*)d_in[17];
    const float* bc2   = (const float*)d_in[18];

    const int* src = ei;
    const int* dst = ei + N_EDGES;

    // workspace layout (all segments 8-B aligned). ghist sits OUTSIDE the
    // zeroed span (stage1 zeroes concurrently with bhist atomics on ghist).
    float* ws        = (float*)d_ws;
    float* Z         = ws;                                      // 8192 floats (cls Z)
    bf16*  ybfA      = (bf16*)(Z + NUM_GRAPHS * HID);           // (N+1)*64 bf16
    bf16*  ybfB      = ybfA + (long)(N_NODES + 1) * HID;        // (N+1)*64 bf16
    int*   cnt       = (int*)(ybfB + (long)(N_NODES + 1) * HID);// 100000 (written by bfill)
    float* pooled    = (float*)(cnt + N_NODES);                 // 4*8*8192 floats
    int*   gcursor   = (int*)(pooled + (long)N_LAYERS * NREP * NUM_GRAPHS * HID); // 256
    int*   gbase     = gcursor + NBKT;                          // 256
    int*   cntg      = gbase + NBKT;                            // 128
    float* zstats    = (float*)(cntg + NUM_GRAPHS);             // 128 (sum | sumsq)
    int*   ghist     = (int*)(zstats + 2 * HID);                // 256 (zeroed in prep)
    int*   col       = ghist + NBKT;                            // 6.4M ints
    int*   epart     = col + (long)N_NODES * CAP;               // 1.6M packed ints
    bf16*  wfrag     = (bf16*)(epart + N_EDGES);                // 7*4096 + 8192 bf16
    // zeroed span: pooled .. zstats (gcursor/gbase/cntg rewritten by bscan)
    const int ZN = N_LAYERS * NREP * NUM_GRAPHS * HID
                 + 2 * NBKT + NUM_GRAPHS + 2 * HID;

    // ---- prep: ghist zero + all weight fragments (before stage1 reads) ----
    prep<<<1 + NWMAT, 256, 0, stream>>>(ghist, W1f, W2f, W2r, W1r, wfrag);

    // ---- stage1: bhist | zero | proj0-MFMA fused (all independent) ----
    stage1<<<PNB + ZB + P0B, 256, 0, stream>>>(
        dst, ghist, (int*)pooled, ZN, x, wfrag + 7 * HID * HID, ybfA);
    bscan<<<1, 256, 0, stream>>>(ghist, gcursor, gbase, batch, cntg, ybfA, ybfB);
    bpart<<<PNB, 256, 0, stream>>>(src, dst, gcursor, epart);
    bfill<<<NBUCK * 4, 256, 0, stream>>>(epart, gbase, ghist, cnt, col);

    // ---- 4 fused layers (16 nodes per block; MFMA MLP, batched gather) ----
    const int NB = N_NODES / 16;                                // 6250
    const long PL = (long)NREP * NUM_GRAPHS * HID;
    const int WM = HID * HID;                                   // 4096 elems / matrix
    layer_fused<true><<<NB, 256, 0, stream>>>(
        ybfA, cnt, col, batch, b1f, wfrag + 0 * WM, b2f,
        wfrag + 4 * WM, ybfB, pooled);
    layer_fused<true><<<NB, 256, 0, stream>>>(
        ybfB, cnt, col, batch, b1r, wfrag + 1 * WM, b2r,
        wfrag + 5 * WM, ybfA, pooled + 1 * PL);
    layer_fused<true><<<NB, 256, 0, stream>>>(
        ybfA, cnt, col, batch, b1r + HID, wfrag + 2 * WM, b2r + HID,
        wfrag + 6 * WM, ybfB, pooled + 2 * PL);
    layer_fused<false><<<NB, 256, 0, stream>>>(
        ybfB, cnt, col, batch, b1r + 2 * HID, wfrag + 3 * WM, b2r + 2 * HID,
        nullptr, nullptr, pooled + 3 * PL);

    // ---- JK + classifier: wide tail (128 blocks each) ----
    jk_cls1<<<NUM_GRAPHS, 256, 0, stream>>>(pooled, cntg, Wjk, bjk, Wc1, bc1,
                                            Z, zstats);
    cls2<<<NUM_GRAPHS, 64, 0, stream>>>(Z, zstats, gamma, beta, Wc2, bc2,
                                        (float*)d_out);
}